// Round 3
// baseline (541.666 us; speedup 1.0000x reference)
//
#include <hip/hip_runtime.h>

constexpr int H = 2048, W = 2048, HW = H * W, MASK = 2047;
constexpr float TEMP = 0.1f;
constexpr float EPS = 1e-8f;
constexpr float SQ2 = 0.70710678118654752440f;

// ---------------------------------------------------------------------------
// Fused kernel. Per 16x16 output tile:
//  phase 1: stage 20x20 halo (offset -2): mass, force, mom, X = A*m + |force|
//  phase 2: per 18x18 ring cell: 4-ch 3x3 conv of X -> force_new; momentum_new
//           (dead-masked); velocity; 9-dir softmax -> LDS. Interior cells also
//           write force_new (f32) to d_out.
//  phase 3: per interior cell: 9-neighbor gather of mass*prop / mom*prop ->
//           new_mass (unnormalized) + new_momentum (f32). Block-reduce
//           sum(mass) and sum(new_mass) -> f64 atomics (16 B of d_ws).
// All force-path arithmetic uses __f*_rn (separate rounding, no contraction)
// to track a plain-numpy f32 evaluation: force errors are amplified by 1/mass
// (min mass ~2e-7) into softmax logits at near-dead cells.
// ---------------------------------------------------------------------------
__global__ __launch_bounds__(256) void k_main(
    const float* __restrict__ mass, const float* __restrict__ mom,
    const float* __restrict__ force, const float* __restrict__ A,
    const float* __restrict__ ker,
    float* __restrict__ out,            // [nm | mom_x | mom_y | f_x | f_y]
    double* __restrict__ sums)          // [sum_mass, sum_new_mass]
{
    __shared__ float XS[400], MS[400], FXs[400], FYs[400], MXs[400], MYs[400];
    __shared__ float PR[9][324];
    __shared__ float PMX[324], PMY[324];
    __shared__ float KS[36];
    __shared__ float wsum0[4], wsum1[4];

    const int tid = threadIdx.x;
    const int bx = blockIdx.x & 127, by = blockIdx.x >> 7;
    const int gx0 = bx << 4, gy0 = by << 4;

    if (tid < 36) KS[tid] = ker[tid];

    // ---- phase 1: stage 20x20 halo (global offset -2) ----
    for (int t = tid; t < 400; t += 256) {
        int py = t / 20, px = t - py * 20;
        int gy = (gy0 + py - 2) & MASK, gx = (gx0 + px - 2) & MASK;
        int idx = gy * W + gx;
        float m  = mass[idx];
        float fx = force[idx], fy = force[idx + HW];
        MS[t] = m; FXs[t] = fx; FYs[t] = fy;
        MXs[t] = mom[idx]; MYs[t] = mom[idx + HW];
        float fn = __fsqrt_rn(__fadd_rn(__fmul_rn(fx, fx), __fmul_rn(fy, fy)));
        XS[t] = __fadd_rn(__fmul_rn(A[idx], m), fn);
    }
    __syncthreads();

    float ksum = 0.f;
#pragma unroll
    for (int i = 0; i < 36; ++i) ksum = __fadd_rn(ksum, fabsf(KS[i]));
    const float kc = 1.0f / ksum;

    const float D0[9] = {SQ2, 0.f, -SQ2, 1.f, 0.f, -1.f, SQ2, 0.f, -SQ2};
    const float D1[9] = {SQ2, 1.f, SQ2, 0.f, 0.f, 0.f, -SQ2, -1.f, -SQ2};

    // ---- phase 2: per 18x18 ring cell ----
    for (int t = tid; t < 324; t += 256) {
        int ly = t / 18, lx = t - ly * 18;
        float nf0 = 0.f, nf1 = 0.f, nf2 = 0.f, nf3 = 0.f;
#pragma unroll
        for (int ky = 0; ky < 3; ++ky)
#pragma unroll
            for (int kx = 0; kx < 3; ++kx) {
                float x = XS[(ly + ky) * 20 + lx + kx];   // cross-correlation
                int j = ky * 3 + kx;
                nf0 = __fadd_rn(nf0, __fmul_rn(KS[j],      x));
                nf1 = __fadd_rn(nf1, __fmul_rn(KS[9 + j],  x));
                nf2 = __fadd_rn(nf2, __fmul_rn(KS[18 + j], x));
                nf3 = __fadd_rn(nf3, __fmul_rn(KS[27 + j], x));
            }
        const int c = (ly + 1) * 20 + lx + 1;             // center in 20x20
        const float fx = FXs[c], fy = FYs[c];
        const float nfx = __fadd_rn(nf0, nf1);                       // sum
        const float nfy = __fmul_rn(__fadd_rn(nf2, nf3), 0.5f);      // mean
        const float fnx = __fadd_rn(fx, __fmul_rn(__fsub_rn(nfx, fx), kc));
        const float fny = __fadd_rn(fy, __fmul_rn(__fsub_rn(nfy, fy), kc));
        const float m = MS[c];
        const bool dead = m < EPS;
        const float pmx = dead ? 0.f : __fadd_rn(MXs[c], fnx);       // DT = 1
        const float pmy = dead ? 0.f : __fadd_rn(MYs[c], fny);
        PMX[t] = pmx; PMY[t] = pmy;
        const float vx = dead ? 0.f : pmx / m;
        const float vy = dead ? 0.f : pmy / m;
        float l[9], lmax = -1e30f;
#pragma unroll
        for (int d = 0; d < 9; ++d) {
            l[d] = __fmul_rn(__fadd_rn(__fmul_rn(D0[d], vx),
                                       __fmul_rn(D1[d], vy)), TEMP);
            lmax = fmaxf(lmax, l[d]);
        }
        float e[9], esum = 0.f;
#pragma unroll
        for (int d = 0; d < 9; ++d) {
            e[d] = expf(__fsub_rn(l[d], lmax));
            esum = __fadd_rn(esum, e[d]);
        }
#pragma unroll
        for (int d = 0; d < 9; ++d) PR[d][t] = e[d] / esum;

        if (ly >= 1 && ly <= 16 && lx >= 1 && lx <= 16) { // interior: force out
            int gidx = (gy0 + ly - 1) * W + gx0 + lx - 1;
            out[3 * HW + gidx] = fnx;
            out[4 * HW + gidx] = fny;
        }
    }
    __syncthreads();

    // ---- phase 3: gather for 16x16 interior ----
    const int tx = tid & 15, ty = tid >> 4;
    float nm = 0.f, omx = 0.f, omy = 0.f;
#pragma unroll
    for (int d = 0; d < 9; ++d) {
        int dy = 1 - d / 3, dx = 1 - d % 3;               // MOVES shift
        int n18 = (ty + 1 + dy) * 18 + tx + 1 + dx;
        int n20 = (ty + 2 + dy) * 20 + tx + 2 + dx;
        float p = PR[d][n18];
        nm  = __fadd_rn(nm,  __fmul_rn(MS[n20],  p));
        omx = __fadd_rn(omx, __fmul_rn(PMX[n18], p));
        omy = __fadd_rn(omy, __fmul_rn(PMY[n18], p));
    }
    const int gidx = (gy0 + ty) * W + gx0 + tx;
    out[gidx]          = nm;                              // unnormalized
    out[HW + gidx]     = omx;
    out[2 * HW + gidx] = omy;

    // ---- block reductions: sum(mass) over interior, sum(new_mass) ----
    float s0 = MS[(ty + 2) * 20 + tx + 2];
    float s1 = nm;
#pragma unroll
    for (int off = 32; off > 0; off >>= 1) {
        s0 += __shfl_down(s0, off);
        s1 += __shfl_down(s1, off);
    }
    if ((tid & 63) == 0) { wsum0[tid >> 6] = s0; wsum1[tid >> 6] = s1; }
    __syncthreads();
    if (tid == 0) {
        atomicAdd(sums,     (double)(wsum0[0] + wsum0[1] + wsum0[2] + wsum0[3]));
        atomicAdd(sums + 1, (double)(wsum1[0] + wsum1[1] + wsum1[2] + wsum1[3]));
    }
}

// ---------------------------------------------------------------------------
// Rescale: new_mass = mass_tot * new_mass / sum(new_mass), in place (f32).
// Mirrors np op order: (mass_tot * nm) then / sum.
// ---------------------------------------------------------------------------
__global__ __launch_bounds__(256) void k_norm(
    float* __restrict__ nm, const double* __restrict__ sums)
{
    const float mt  = (float)sums[0];
    const float snm = (float)sums[1];
    const int i = blockIdx.x * 256 + threadIdx.x;
    nm[i] = __fmul_rn(mt, nm[i]) / snm;
}

extern "C" void kernel_launch(void* const* d_in, const int* in_sizes, int n_in,
                              void* d_out, int out_size, void* d_ws, size_t ws_size,
                              hipStream_t stream)
{
    const float* mass  = (const float*)d_in[0];
    const float* mom   = (const float*)d_in[1];
    const float* force = (const float*)d_in[2];
    const float* A     = (const float*)d_in[3];
    const float* ker   = (const float*)d_in[4];
    float* out = (float*)d_out;

    double* sums = (double*)d_ws;                 // 16 bytes only
    hipMemsetAsync(sums, 0, 2 * sizeof(double), stream);

    k_main<<<dim3(128 * 128), dim3(256), 0, stream>>>(mass, mom, force, A, ker,
                                                      out, sums);
    k_norm<<<dim3(HW / 256), dim3(256), 0, stream>>>(out, sums);
}

// Round 4
// 539.137 us; speedup vs baseline: 1.0047x; 1.0047x over previous
//
#include <hip/hip_runtime.h>

constexpr int H = 2048, W = 2048, HW = H * W, MASK = 2047;
constexpr float TEMP = 0.1f;
constexpr float EPS = 1e-8f;
constexpr float SQ2 = 0.70710678118654752440f;

// ---------------------------------------------------------------------------
// Fused kernel, 16x16 interior tile per 256-thread block.
//  phase 1: stage ONLY X = A*m + |force| on a 20-row x 24-col halo
//           (y: -2..17, x: -4..19; 24-wide keeps float2 pair bases aligned
//           under wrap). 240 float2 items -> one iteration, 4 vec loads/thread.
//  phase 2: per 18x18 ring cell: 4-ch 3x3 conv of XS -> force_new; own-cell
//           mass/force/mom re-read from global (L1-warm); momentum_new,
//           velocity, 9-dir softmax -> compact 18x18 LDS planes. Interior
//           cells write force_new (f32) to d_out.
//  phase 3: per interior cell: 9-neighbor gather -> new_mass (unnorm) +
//           new_momentum. Block-reduce sum(mass), sum(new_mass) -> f64 atomics.
// LDS ~17.3 KiB (was 24) -> 8 blocks/CU wave-capped; force-path math kept in
// strict __f*_rn order (np-matching; 1/mass amplifies force error into logits).
// ---------------------------------------------------------------------------
__global__ __launch_bounds__(256) void k_main(
    const float* __restrict__ mass, const float* __restrict__ mom,
    const float* __restrict__ force, const float* __restrict__ A,
    const float* __restrict__ ker,
    float* __restrict__ out,            // [nm | mom_x | mom_y | f_x | f_y]
    double* __restrict__ sums)          // [sum_mass, sum_new_mass]
{
    __shared__ float XS[20 * 24];
    __shared__ float MS[324], PMX[324], PMY[324];
    __shared__ float PR[9][324];
    __shared__ float KS[36];
    __shared__ float wsum0[4], wsum1[4];

    const int tid = threadIdx.x;
    const int bx = blockIdx.x & 127, by = blockIdx.x >> 7;
    const int gx0 = bx << 4, gy0 = by << 4;

    if (tid < 36) KS[tid] = ker[tid];

    // ---- phase 1: stage X on 20x24 halo, float2 loads ----
    if (tid < 240) {
        const int py = tid / 12, px2 = (tid - py * 12) * 2;   // col pair 0..22
        const int gy = (gy0 + py - 2) & MASK;
        const int gxp = (gx0 + px2 - 4) & MASK;               // even, no row cross
        const int idx = gy * W + gxp;
        const float2 m2 = *(const float2*)(mass + idx);
        const float2 a2 = *(const float2*)(A + idx);
        const float2 fx2 = *(const float2*)(force + idx);
        const float2 fy2 = *(const float2*)(force + HW + idx);
        float x0 = __fadd_rn(__fmul_rn(a2.x, m2.x),
            __fsqrt_rn(__fadd_rn(__fmul_rn(fx2.x, fx2.x), __fmul_rn(fy2.x, fy2.x))));
        float x1 = __fadd_rn(__fmul_rn(a2.y, m2.y),
            __fsqrt_rn(__fadd_rn(__fmul_rn(fx2.y, fx2.y), __fmul_rn(fy2.y, fy2.y))));
        *(float2*)&XS[py * 24 + px2] = make_float2(x0, x1);
    }
    __syncthreads();

    float ksum = 0.f;
#pragma unroll
    for (int i = 0; i < 36; ++i) ksum = __fadd_rn(ksum, fabsf(KS[i]));
    const float kc = 1.0f / ksum;

    const float D0[9] = {SQ2, 0.f, -SQ2, 1.f, 0.f, -1.f, SQ2, 0.f, -SQ2};
    const float D1[9] = {SQ2, 1.f, SQ2, 0.f, 0.f, 0.f, -SQ2, -1.f, -SQ2};

    // ---- phase 2: per 18x18 ring cell ----
    for (int t = tid; t < 324; t += 256) {
        const int ly = t / 18, lx = t - ly * 18;
        // own-cell globals first (independent of LDS; L1-warm for m/f)
        const int gy = (gy0 + ly - 1) & MASK, gx = (gx0 + lx - 1) & MASK;
        const int idx = gy * W + gx;
        const float m  = mass[idx];
        const float fx = force[idx], fy = force[idx + HW];
        const float mx = mom[idx],   my = mom[idx + HW];

        float nf0 = 0.f, nf1 = 0.f, nf2 = 0.f, nf3 = 0.f;
#pragma unroll
        for (int ky = 0; ky < 3; ++ky)
#pragma unroll
            for (int kx = 0; kx < 3; ++kx) {
                const float x = XS[(ly + ky) * 24 + lx + kx + 2];
                const int j = ky * 3 + kx;
                nf0 = __fadd_rn(nf0, __fmul_rn(KS[j],      x));
                nf1 = __fadd_rn(nf1, __fmul_rn(KS[9 + j],  x));
                nf2 = __fadd_rn(nf2, __fmul_rn(KS[18 + j], x));
                nf3 = __fadd_rn(nf3, __fmul_rn(KS[27 + j], x));
            }
        const float nfx = __fadd_rn(nf0, nf1);                     // sum
        const float nfy = __fmul_rn(__fadd_rn(nf2, nf3), 0.5f);    // mean
        const float fnx = __fadd_rn(fx, __fmul_rn(__fsub_rn(nfx, fx), kc));
        const float fny = __fadd_rn(fy, __fmul_rn(__fsub_rn(nfy, fy), kc));
        const bool dead = m < EPS;
        const float pmx = dead ? 0.f : __fadd_rn(mx, fnx);         // DT = 1
        const float pmy = dead ? 0.f : __fadd_rn(my, fny);
        MS[t] = m; PMX[t] = pmx; PMY[t] = pmy;
        const float vx = dead ? 0.f : pmx / m;
        const float vy = dead ? 0.f : pmy / m;
        float l[9], lmax = -1e30f;
#pragma unroll
        for (int d = 0; d < 9; ++d) {
            l[d] = __fmul_rn(__fadd_rn(__fmul_rn(D0[d], vx),
                                       __fmul_rn(D1[d], vy)), TEMP);
            lmax = fmaxf(lmax, l[d]);
        }
        float e[9], esum = 0.f;
#pragma unroll
        for (int d = 0; d < 9; ++d) {
            e[d] = expf(__fsub_rn(l[d], lmax));
            esum = __fadd_rn(esum, e[d]);
        }
        const float inv = 1.0f / esum;
#pragma unroll
        for (int d = 0; d < 9; ++d) PR[d][t] = __fmul_rn(e[d], inv);

        if (ly >= 1 && ly <= 16 && lx >= 1 && lx <= 16) {          // interior
            const int gidx = (gy0 + ly - 1) * W + gx0 + lx - 1;
            out[3 * HW + gidx] = fnx;
            out[4 * HW + gidx] = fny;
        }
    }
    __syncthreads();

    // ---- phase 3: gather for 16x16 interior ----
    const int tx = tid & 15, ty = tid >> 4;
    float nm = 0.f, omx = 0.f, omy = 0.f;
#pragma unroll
    for (int d = 0; d < 9; ++d) {
        const int dy = 1 - d / 3, dx = 1 - d % 3;                  // MOVES shift
        const int n = (ty + 1 + dy) * 18 + tx + 1 + dx;
        const float p = PR[d][n];
        nm  = __fadd_rn(nm,  __fmul_rn(MS[n],  p));
        omx = __fadd_rn(omx, __fmul_rn(PMX[n], p));
        omy = __fadd_rn(omy, __fmul_rn(PMY[n], p));
    }
    const int gidx = (gy0 + ty) * W + gx0 + tx;
    out[gidx]          = nm;                                       // unnormalized
    out[HW + gidx]     = omx;
    out[2 * HW + gidx] = omy;

    // ---- block reductions ----
    float s0 = MS[(ty + 1) * 18 + tx + 1];                         // own mass
    float s1 = nm;
#pragma unroll
    for (int off = 32; off > 0; off >>= 1) {
        s0 += __shfl_down(s0, off);
        s1 += __shfl_down(s1, off);
    }
    if ((tid & 63) == 0) { wsum0[tid >> 6] = s0; wsum1[tid >> 6] = s1; }
    __syncthreads();
    if (tid == 0) {
        atomicAdd(sums,     (double)(wsum0[0] + wsum0[1] + wsum0[2] + wsum0[3]));
        atomicAdd(sums + 1, (double)(wsum1[0] + wsum1[1] + wsum1[2] + wsum1[3]));
    }
}

// ---------------------------------------------------------------------------
// Rescale: new_mass = mass_tot * new_mass / sum(new_mass), in place, float4.
// ---------------------------------------------------------------------------
__global__ __launch_bounds__(256) void k_norm(
    float* __restrict__ nm, const double* __restrict__ sums)
{
    const float mt  = (float)sums[0];
    const float snm = (float)sums[1];
    const int i = (blockIdx.x * 256 + threadIdx.x) * 4;
    float4 v = *(float4*)(nm + i);
    v.x = __fmul_rn(mt, v.x) / snm;
    v.y = __fmul_rn(mt, v.y) / snm;
    v.z = __fmul_rn(mt, v.z) / snm;
    v.w = __fmul_rn(mt, v.w) / snm;
    *(float4*)(nm + i) = v;
}

extern "C" void kernel_launch(void* const* d_in, const int* in_sizes, int n_in,
                              void* d_out, int out_size, void* d_ws, size_t ws_size,
                              hipStream_t stream)
{
    const float* mass  = (const float*)d_in[0];
    const float* mom   = (const float*)d_in[1];
    const float* force = (const float*)d_in[2];
    const float* A     = (const float*)d_in[3];
    const float* ker   = (const float*)d_in[4];
    float* out = (float*)d_out;

    double* sums = (double*)d_ws;                 // 16 bytes only
    hipMemsetAsync(sums, 0, 2 * sizeof(double), stream);

    k_main<<<dim3(128 * 128), dim3(256), 0, stream>>>(mass, mom, force, A, ker,
                                                      out, sums);
    k_norm<<<dim3(HW / 1024), dim3(256), 0, stream>>>(out, sums);
}

// Round 5
// 249.692 us; speedup vs baseline: 2.1693x; 2.1592x over previous
//
#include <hip/hip_runtime.h>

constexpr int H = 2048, W = 2048, HW = H * W, MASK = 2047;
constexpr float TEMP = 0.1f;
constexpr float EPS = 1e-8f;
constexpr float SQ2 = 0.70710678118654752440f;
constexpr int NACC = 128;   // accumulator slots per sum, one cache line each

// ---------------------------------------------------------------------------
// Fused kernel, 16x16 interior tile per 256-thread block. Structure identical
// to round 4 EXCEPT the final reduction: per-block sums go to one of NACC=128
// cache-line-spread f64 accumulators (d_ws, stride-8 doubles) instead of a
// single same-line pair. Round 3/4 showed 411us invariant with all pipes idle:
// 32768 same-line f64 atomics serialized (~12.5ns each ~= 410us drain).
// ---------------------------------------------------------------------------
__global__ __launch_bounds__(256) void k_main(
    const float* __restrict__ mass, const float* __restrict__ mom,
    const float* __restrict__ force, const float* __restrict__ A,
    const float* __restrict__ ker,
    float* __restrict__ out,            // [nm | mom_x | mom_y | f_x | f_y]
    double* __restrict__ acc)           // [NACC*8 for mass | NACC*8 for nm]
{
    __shared__ float XS[20 * 24];
    __shared__ float MS[324], PMX[324], PMY[324];
    __shared__ float PR[9][324];
    __shared__ float KS[36];
    __shared__ float wsum0[4], wsum1[4];

    const int tid = threadIdx.x;
    const int bx = blockIdx.x & 127, by = blockIdx.x >> 7;
    const int gx0 = bx << 4, gy0 = by << 4;

    if (tid < 36) KS[tid] = ker[tid];

    // ---- phase 1: stage X on 20x24 halo, float2 loads ----
    if (tid < 240) {
        const int py = tid / 12, px2 = (tid - py * 12) * 2;   // col pair 0..22
        const int gy = (gy0 + py - 2) & MASK;
        const int gxp = (gx0 + px2 - 4) & MASK;               // even, no row cross
        const int idx = gy * W + gxp;
        const float2 m2 = *(const float2*)(mass + idx);
        const float2 a2 = *(const float2*)(A + idx);
        const float2 fx2 = *(const float2*)(force + idx);
        const float2 fy2 = *(const float2*)(force + HW + idx);
        float x0 = __fadd_rn(__fmul_rn(a2.x, m2.x),
            __fsqrt_rn(__fadd_rn(__fmul_rn(fx2.x, fx2.x), __fmul_rn(fy2.x, fy2.x))));
        float x1 = __fadd_rn(__fmul_rn(a2.y, m2.y),
            __fsqrt_rn(__fadd_rn(__fmul_rn(fx2.y, fx2.y), __fmul_rn(fy2.y, fy2.y))));
        *(float2*)&XS[py * 24 + px2] = make_float2(x0, x1);
    }
    __syncthreads();

    float ksum = 0.f;
#pragma unroll
    for (int i = 0; i < 36; ++i) ksum = __fadd_rn(ksum, fabsf(KS[i]));
    const float kc = 1.0f / ksum;

    const float D0[9] = {SQ2, 0.f, -SQ2, 1.f, 0.f, -1.f, SQ2, 0.f, -SQ2};
    const float D1[9] = {SQ2, 1.f, SQ2, 0.f, 0.f, 0.f, -SQ2, -1.f, -SQ2};

    // ---- phase 2: per 18x18 ring cell ----
    for (int t = tid; t < 324; t += 256) {
        const int ly = t / 18, lx = t - ly * 18;
        const int gy = (gy0 + ly - 1) & MASK, gx = (gx0 + lx - 1) & MASK;
        const int idx = gy * W + gx;
        const float m  = mass[idx];
        const float fx = force[idx], fy = force[idx + HW];
        const float mx = mom[idx],   my = mom[idx + HW];

        float nf0 = 0.f, nf1 = 0.f, nf2 = 0.f, nf3 = 0.f;
#pragma unroll
        for (int ky = 0; ky < 3; ++ky)
#pragma unroll
            for (int kx = 0; kx < 3; ++kx) {
                const float x = XS[(ly + ky) * 24 + lx + kx + 2];
                const int j = ky * 3 + kx;
                nf0 = __fadd_rn(nf0, __fmul_rn(KS[j],      x));
                nf1 = __fadd_rn(nf1, __fmul_rn(KS[9 + j],  x));
                nf2 = __fadd_rn(nf2, __fmul_rn(KS[18 + j], x));
                nf3 = __fadd_rn(nf3, __fmul_rn(KS[27 + j], x));
            }
        const float nfx = __fadd_rn(nf0, nf1);                     // sum
        const float nfy = __fmul_rn(__fadd_rn(nf2, nf3), 0.5f);    // mean
        const float fnx = __fadd_rn(fx, __fmul_rn(__fsub_rn(nfx, fx), kc));
        const float fny = __fadd_rn(fy, __fmul_rn(__fsub_rn(nfy, fy), kc));
        const bool dead = m < EPS;
        const float pmx = dead ? 0.f : __fadd_rn(mx, fnx);         // DT = 1
        const float pmy = dead ? 0.f : __fadd_rn(my, fny);
        MS[t] = m; PMX[t] = pmx; PMY[t] = pmy;
        const float vx = dead ? 0.f : pmx / m;
        const float vy = dead ? 0.f : pmy / m;
        float l[9], lmax = -1e30f;
#pragma unroll
        for (int d = 0; d < 9; ++d) {
            l[d] = __fmul_rn(__fadd_rn(__fmul_rn(D0[d], vx),
                                       __fmul_rn(D1[d], vy)), TEMP);
            lmax = fmaxf(lmax, l[d]);
        }
        float e[9], esum = 0.f;
#pragma unroll
        for (int d = 0; d < 9; ++d) {
            e[d] = expf(__fsub_rn(l[d], lmax));
            esum = __fadd_rn(esum, e[d]);
        }
        const float inv = 1.0f / esum;
#pragma unroll
        for (int d = 0; d < 9; ++d) PR[d][t] = __fmul_rn(e[d], inv);

        if (ly >= 1 && ly <= 16 && lx >= 1 && lx <= 16) {          // interior
            const int gidx = (gy0 + ly - 1) * W + gx0 + lx - 1;
            out[3 * HW + gidx] = fnx;
            out[4 * HW + gidx] = fny;
        }
    }
    __syncthreads();

    // ---- phase 3: gather for 16x16 interior ----
    const int tx = tid & 15, ty = tid >> 4;
    float nm = 0.f, omx = 0.f, omy = 0.f;
#pragma unroll
    for (int d = 0; d < 9; ++d) {
        const int dy = 1 - d / 3, dx = 1 - d % 3;                  // MOVES shift
        const int n = (ty + 1 + dy) * 18 + tx + 1 + dx;
        const float p = PR[d][n];
        nm  = __fadd_rn(nm,  __fmul_rn(MS[n],  p));
        omx = __fadd_rn(omx, __fmul_rn(PMX[n], p));
        omy = __fadd_rn(omy, __fmul_rn(PMY[n], p));
    }
    const int gidx = (gy0 + ty) * W + gx0 + tx;
    out[gidx]          = nm;                                       // unnormalized
    out[HW + gidx]     = omx;
    out[2 * HW + gidx] = omy;

    // ---- block reductions -> line-spread f64 accumulators ----
    float s0 = MS[(ty + 1) * 18 + tx + 1];                         // own mass
    float s1 = nm;
#pragma unroll
    for (int off = 32; off > 0; off >>= 1) {
        s0 += __shfl_down(s0, off);
        s1 += __shfl_down(s1, off);
    }
    if ((tid & 63) == 0) { wsum0[tid >> 6] = s0; wsum1[tid >> 6] = s1; }
    __syncthreads();
    if (tid == 0) {
        const int slot = (blockIdx.x & (NACC - 1)) * 8;            // own line
        atomicAdd(acc + slot,
                  (double)(wsum0[0] + wsum0[1] + wsum0[2] + wsum0[3]));
        atomicAdd(acc + NACC * 8 + slot,
                  (double)(wsum1[0] + wsum1[1] + wsum1[2] + wsum1[3]));
    }
}

// ---------------------------------------------------------------------------
// Rescale: reduce the 2*NACC partials in-register (lane-parallel + shuffle),
// then new_mass = mass_tot * new_mass / sum(new_mass), in place, float4.
// ---------------------------------------------------------------------------
__global__ __launch_bounds__(256) void k_norm(
    float* __restrict__ nm, const double* __restrict__ acc)
{
    const int lane = threadIdx.x & 63;
    double s0 = 0.0, s1 = 0.0;
#pragma unroll
    for (int i = 0; i < NACC / 64; ++i) {                // 2 slots per lane
        const int slot = (lane + i * 64) * 8;
        s0 += acc[slot];
        s1 += acc[NACC * 8 + slot];
    }
#pragma unroll
    for (int off = 32; off > 0; off >>= 1) {
        s0 += __shfl_down(s0, off);
        s1 += __shfl_down(s1, off);
    }
    const float mt  = (float)__shfl(s0, 0);
    const float snm = (float)__shfl(s1, 0);

    const int i = (blockIdx.x * 256 + threadIdx.x) * 4;
    float4 v = *(float4*)(nm + i);
    v.x = __fmul_rn(mt, v.x) / snm;
    v.y = __fmul_rn(mt, v.y) / snm;
    v.z = __fmul_rn(mt, v.z) / snm;
    v.w = __fmul_rn(mt, v.w) / snm;
    *(float4*)(nm + i) = v;
}

extern "C" void kernel_launch(void* const* d_in, const int* in_sizes, int n_in,
                              void* d_out, int out_size, void* d_ws, size_t ws_size,
                              hipStream_t stream)
{
    const float* mass  = (const float*)d_in[0];
    const float* mom   = (const float*)d_in[1];
    const float* force = (const float*)d_in[2];
    const float* A     = (const float*)d_in[3];
    const float* ker   = (const float*)d_in[4];
    float* out = (float*)d_out;

    double* acc = (double*)d_ws;                  // 2 * NACC * 8 doubles = 16 KiB
    hipMemsetAsync(acc, 0, 2 * NACC * 8 * sizeof(double), stream);

    k_main<<<dim3(128 * 128), dim3(256), 0, stream>>>(mass, mom, force, A, ker,
                                                      out, acc);
    k_norm<<<dim3(HW / 1024), dim3(256), 0, stream>>>(out, acc);
}

// Round 6
// 222.286 us; speedup vs baseline: 2.4368x; 1.1233x over previous
//
#include <hip/hip_runtime.h>

constexpr int H = 2048, W = 2048, HW = H * W, MASK = 2047;
constexpr float TEMP = 0.1f;
constexpr float EPS = 1e-8f;
constexpr float SQ2 = 0.70710678118654752440f;
constexpr int NACC = 128;   // accumulator slots per sum, one cache line each

// ---------------------------------------------------------------------------
// Fused kernel, 16x16 interior tile per 256-thread block.
// vs round 5 (122us, VALU 55%, FETCH 225MB):
//  * expf -> __expf (native v_exp_f32): ~25% VALU cut. Safe: exp error enters
//    prop multiplicatively (~1e-6 rel), not through the l-lmax difference that
//    gets amplified at near-dead cells. Danger path (conv/force/velocity/
//    logits) kept byte-identical to preserve the passing 0.0156 draw.
//  * XCD-aware swizzle: blocks dispatch round-robin to 8 XCDs; map xcd=b&7 to
//    a contiguous 16-tile-row slab so halo sharing is XCD-local. Expect
//    FETCH 225 -> ~130MB (L2 over-fetch was cross-XCD halo duplication).
// ---------------------------------------------------------------------------
__global__ __launch_bounds__(256) void k_main(
    const float* __restrict__ mass, const float* __restrict__ mom,
    const float* __restrict__ force, const float* __restrict__ A,
    const float* __restrict__ ker,
    float* __restrict__ out,            // [nm | mom_x | mom_y | f_x | f_y]
    double* __restrict__ acc)           // [NACC*8 for mass | NACC*8 for nm]
{
    __shared__ float XS[20 * 24];
    __shared__ float MS[324], PMX[324], PMY[324];
    __shared__ float PR[9][324];
    __shared__ float KS[36];
    __shared__ float wsum0[4], wsum1[4];

    const int tid = threadIdx.x;
    // XCD-aware tile mapping: xcd = b&7 owns tile rows [xcd*16, xcd*16+16)
    const int b = blockIdx.x;
    const int xcd = b & 7, r = b >> 3;
    const int by = (xcd << 4) | (r >> 7), bx = r & 127;
    const int gx0 = bx << 4, gy0 = by << 4;

    if (tid < 36) KS[tid] = ker[tid];

    // ---- phase 1: stage X on 20x24 halo, float2 loads ----
    if (tid < 240) {
        const int py = tid / 12, px2 = (tid - py * 12) * 2;   // col pair 0..22
        const int gy = (gy0 + py - 2) & MASK;
        const int gxp = (gx0 + px2 - 4) & MASK;               // even, no row cross
        const int idx = gy * W + gxp;
        const float2 m2 = *(const float2*)(mass + idx);
        const float2 a2 = *(const float2*)(A + idx);
        const float2 fx2 = *(const float2*)(force + idx);
        const float2 fy2 = *(const float2*)(force + HW + idx);
        float x0 = __fadd_rn(__fmul_rn(a2.x, m2.x),
            __fsqrt_rn(__fadd_rn(__fmul_rn(fx2.x, fx2.x), __fmul_rn(fy2.x, fy2.x))));
        float x1 = __fadd_rn(__fmul_rn(a2.y, m2.y),
            __fsqrt_rn(__fadd_rn(__fmul_rn(fx2.y, fx2.y), __fmul_rn(fy2.y, fy2.y))));
        *(float2*)&XS[py * 24 + px2] = make_float2(x0, x1);
    }
    __syncthreads();

    float ksum = 0.f;
#pragma unroll
    for (int i = 0; i < 36; ++i) ksum = __fadd_rn(ksum, fabsf(KS[i]));
    const float kc = 1.0f / ksum;

    const float D0[9] = {SQ2, 0.f, -SQ2, 1.f, 0.f, -1.f, SQ2, 0.f, -SQ2};
    const float D1[9] = {SQ2, 1.f, SQ2, 0.f, 0.f, 0.f, -SQ2, -1.f, -SQ2};

    // ---- phase 2: per 18x18 ring cell ----
    for (int t = tid; t < 324; t += 256) {
        const int ly = t / 18, lx = t - ly * 18;
        const int gy = (gy0 + ly - 1) & MASK, gx = (gx0 + lx - 1) & MASK;
        const int idx = gy * W + gx;
        const float m  = mass[idx];
        const float fx = force[idx], fy = force[idx + HW];
        const float mx = mom[idx],   my = mom[idx + HW];

        float nf0 = 0.f, nf1 = 0.f, nf2 = 0.f, nf3 = 0.f;
#pragma unroll
        for (int ky = 0; ky < 3; ++ky)
#pragma unroll
            for (int kx = 0; kx < 3; ++kx) {
                const float x = XS[(ly + ky) * 24 + lx + kx + 2];
                const int j = ky * 3 + kx;
                nf0 = __fadd_rn(nf0, __fmul_rn(KS[j],      x));
                nf1 = __fadd_rn(nf1, __fmul_rn(KS[9 + j],  x));
                nf2 = __fadd_rn(nf2, __fmul_rn(KS[18 + j], x));
                nf3 = __fadd_rn(nf3, __fmul_rn(KS[27 + j], x));
            }
        const float nfx = __fadd_rn(nf0, nf1);                     // sum
        const float nfy = __fmul_rn(__fadd_rn(nf2, nf3), 0.5f);    // mean
        const float fnx = __fadd_rn(fx, __fmul_rn(__fsub_rn(nfx, fx), kc));
        const float fny = __fadd_rn(fy, __fmul_rn(__fsub_rn(nfy, fy), kc));
        const bool dead = m < EPS;
        const float pmx = dead ? 0.f : __fadd_rn(mx, fnx);         // DT = 1
        const float pmy = dead ? 0.f : __fadd_rn(my, fny);
        MS[t] = m; PMX[t] = pmx; PMY[t] = pmy;
        const float vx = dead ? 0.f : pmx / m;
        const float vy = dead ? 0.f : pmy / m;
        float l[9], lmax = -1e30f;
#pragma unroll
        for (int d = 0; d < 9; ++d) {
            l[d] = __fmul_rn(__fadd_rn(__fmul_rn(D0[d], vx),
                                       __fmul_rn(D1[d], vy)), TEMP);
            lmax = fmaxf(lmax, l[d]);
        }
        float e[9], esum = 0.f;
#pragma unroll
        for (int d = 0; d < 9; ++d) {
            e[d] = __expf(__fsub_rn(l[d], lmax));   // native v_exp_f32
            esum = __fadd_rn(esum, e[d]);
        }
        const float inv = 1.0f / esum;
#pragma unroll
        for (int d = 0; d < 9; ++d) PR[d][t] = __fmul_rn(e[d], inv);

        if (ly >= 1 && ly <= 16 && lx >= 1 && lx <= 16) {          // interior
            const int gidx = (gy0 + ly - 1) * W + gx0 + lx - 1;
            out[3 * HW + gidx] = fnx;
            out[4 * HW + gidx] = fny;
        }
    }
    __syncthreads();

    // ---- phase 3: gather for 16x16 interior ----
    const int tx = tid & 15, ty = tid >> 4;
    float nm = 0.f, omx = 0.f, omy = 0.f;
#pragma unroll
    for (int d = 0; d < 9; ++d) {
        const int dy = 1 - d / 3, dx = 1 - d % 3;                  // MOVES shift
        const int n = (ty + 1 + dy) * 18 + tx + 1 + dx;
        const float p = PR[d][n];
        nm  = __fadd_rn(nm,  __fmul_rn(MS[n],  p));
        omx = __fadd_rn(omx, __fmul_rn(PMX[n], p));
        omy = __fadd_rn(omy, __fmul_rn(PMY[n], p));
    }
    const int gidx = (gy0 + ty) * W + gx0 + tx;
    out[gidx]          = nm;                                       // unnormalized
    out[HW + gidx]     = omx;
    out[2 * HW + gidx] = omy;

    // ---- block reductions -> line-spread f64 accumulators ----
    float s0 = MS[(ty + 1) * 18 + tx + 1];                         // own mass
    float s1 = nm;
#pragma unroll
    for (int off = 32; off > 0; off >>= 1) {
        s0 += __shfl_down(s0, off);
        s1 += __shfl_down(s1, off);
    }
    if ((tid & 63) == 0) { wsum0[tid >> 6] = s0; wsum1[tid >> 6] = s1; }
    __syncthreads();
    if (tid == 0) {
        const int slot = (blockIdx.x & (NACC - 1)) * 8;            // own line
        atomicAdd(acc + slot,
                  (double)(wsum0[0] + wsum0[1] + wsum0[2] + wsum0[3]));
        atomicAdd(acc + NACC * 8 + slot,
                  (double)(wsum1[0] + wsum1[1] + wsum1[2] + wsum1[3]));
    }
}

// ---------------------------------------------------------------------------
// Rescale: reduce the 2*NACC partials in-register (lane-parallel + shuffle),
// then new_mass = mass_tot * new_mass / sum(new_mass), in place, float4.
// ---------------------------------------------------------------------------
__global__ __launch_bounds__(256) void k_norm(
    float* __restrict__ nm, const double* __restrict__ acc)
{
    const int lane = threadIdx.x & 63;
    double s0 = 0.0, s1 = 0.0;
#pragma unroll
    for (int i = 0; i < NACC / 64; ++i) {                // 2 slots per lane
        const int slot = (lane + i * 64) * 8;
        s0 += acc[slot];
        s1 += acc[NACC * 8 + slot];
    }
#pragma unroll
    for (int off = 32; off > 0; off >>= 1) {
        s0 += __shfl_down(s0, off);
        s1 += __shfl_down(s1, off);
    }
    const float mt  = (float)__shfl(s0, 0);
    const float snm = (float)__shfl(s1, 0);

    const int i = (blockIdx.x * 256 + threadIdx.x) * 4;
    float4 v = *(float4*)(nm + i);
    v.x = __fmul_rn(mt, v.x) / snm;
    v.y = __fmul_rn(mt, v.y) / snm;
    v.z = __fmul_rn(mt, v.z) / snm;
    v.w = __fmul_rn(mt, v.w) / snm;
    *(float4*)(nm + i) = v;
}

extern "C" void kernel_launch(void* const* d_in, const int* in_sizes, int n_in,
                              void* d_out, int out_size, void* d_ws, size_t ws_size,
                              hipStream_t stream)
{
    const float* mass  = (const float*)d_in[0];
    const float* mom   = (const float*)d_in[1];
    const float* force = (const float*)d_in[2];
    const float* A     = (const float*)d_in[3];
    const float* ker   = (const float*)d_in[4];
    float* out = (float*)d_out;

    double* acc = (double*)d_ws;                  // 2 * NACC * 8 doubles = 16 KiB
    hipMemsetAsync(acc, 0, 2 * NACC * 8 * sizeof(double), stream);

    k_main<<<dim3(128 * 128), dim3(256), 0, stream>>>(mass, mom, force, A, ker,
                                                      out, acc);
    k_norm<<<dim3(HW / 1024), dim3(256), 0, stream>>>(out, acc);
}